// Round 8
// baseline (1583.657 us; speedup 1.0000x reference)
//
#include <hip/hip_runtime.h>
#include <hip/hip_bf16.h>
#include <cstdint>

#define B_ 16
#define N_ 4096
#define CPTS_ 64
#define M_ 1024
#define K_ 32

using ushort8 = __attribute__((ext_vector_type(8))) unsigned short;
using f32x2 = __attribute__((ext_vector_type(2))) float;

static __device__ __forceinline__ unsigned f2bf(float x){
  unsigned u = __float_as_uint(x);
  return (u + 0x7fffu + ((u >> 16) & 1u)) >> 16;   // RTNE
}
static __device__ __forceinline__ float bf2f(unsigned short u){
  return __uint_as_float(((unsigned)u) << 16);
}

// DPP max step: v = max(v, dpp_shift(v)). Values are >= 0 so 0-fill is identity.
#define DPPMAX(v, ctrl)                                                        \
  do {                                                                         \
    int _t = __builtin_amdgcn_update_dpp(0, __float_as_int(v), (ctrl), 0xf,    \
                                         0xf, true);                           \
    (v) = fmaxf((v), __int_as_float(_t));                                      \
  } while (0)

// Pair distance update on f32x2 (emits v_pk_sub/mul/add on gfx950).
// Per-element op sequence identical to the scalar passing versions:
// dx=px-cx; d=dx*dx; d=d+dy*dy; d=d+dz*dz; md=min(md,d). contract(off).
#define PSTEP(MD, PX, PY, PZ)                                                  \
  { f32x2 dx = PX - cx2, dy = PY - cy2, dz = PZ - cz2;                         \
    f32x2 t0 = dx * dx, t1 = dy * dy, t2 = dz * dz;                            \
    f32x2 d = t0; d = d + t1; d = d + t2;                                      \
    MD = __builtin_elementwise_min(MD, d); }

// ---------------- FPS: one block per batch, sequential argmax chain ---------
// R8: packed-f32 update (pk ops halve VALU issue), value-only max tree,
// winner-lane j/coord reconstruction, coords carried through LDS slots
// (removes the dependent xs[far] broadcast fetch from the iteration chain).
__global__ __launch_bounds__(512, 1) void fps_kernel(const float* __restrict__ xyz,
                                                     float* __restrict__ newxyz){
#pragma clang fp contract(off)
  __shared__ float xs[N_], ys[N_], zs[N_];
  __shared__ int inds_s[M_];
  __shared__ unsigned long long sv_[2][8];
  __shared__ __align__(16) float4 sc_[2][8];
  const int b = blockIdx.x, tid = threadIdx.x;
  const int lane = tid & 63, wv = tid >> 6;
  const float* xb = xyz + (size_t)b * N_ * 3;
  for (int i = tid; i < N_ * 3; i += 512){
    float v = xb[i];
    int n = i / 3, c = i - n * 3;
    if (c == 0) xs[n] = v; else if (c == 1) ys[n] = v; else zs[n] = v;
  }
  __syncthreads();
  // per-lane points: n = tid*8 + j  (wave w owns [w*512, w*512+512))
  const f32x2 px01 = *reinterpret_cast<const f32x2*>(&xs[tid * 8 + 0]);
  const f32x2 px23 = *reinterpret_cast<const f32x2*>(&xs[tid * 8 + 2]);
  const f32x2 px45 = *reinterpret_cast<const f32x2*>(&xs[tid * 8 + 4]);
  const f32x2 px67 = *reinterpret_cast<const f32x2*>(&xs[tid * 8 + 6]);
  const f32x2 py01 = *reinterpret_cast<const f32x2*>(&ys[tid * 8 + 0]);
  const f32x2 py23 = *reinterpret_cast<const f32x2*>(&ys[tid * 8 + 2]);
  const f32x2 py45 = *reinterpret_cast<const f32x2*>(&ys[tid * 8 + 4]);
  const f32x2 py67 = *reinterpret_cast<const f32x2*>(&ys[tid * 8 + 6]);
  const f32x2 pz01 = *reinterpret_cast<const f32x2*>(&zs[tid * 8 + 0]);
  const f32x2 pz23 = *reinterpret_cast<const f32x2*>(&zs[tid * 8 + 2]);
  const f32x2 pz45 = *reinterpret_cast<const f32x2*>(&zs[tid * 8 + 4]);
  const f32x2 pz67 = *reinterpret_cast<const f32x2*>(&zs[tid * 8 + 6]);
  f32x2 md01 = {1e10f, 1e10f}, md23 = md01, md45 = md01, md67 = md01;
  int far = 0;
  float cx = xs[0], cy = ys[0], cz = zs[0];
  for (int m = 0; m < M_; ++m){
    if (tid == 0) inds_s[m] = far;
    const f32x2 cx2 = {cx, cx}, cy2 = {cy, cy}, cz2 = {cz, cz};
    PSTEP(md01, px01, py01, pz01)
    PSTEP(md23, px23, py23, pz23)
    PSTEP(md45, px45, py45, pz45)
    PSTEP(md67, px67, py67, pz67)
    // per-lane max (value only — j reconstructed on the winner path)
    f32x2 e0 = __builtin_elementwise_max(md01, md23);
    f32x2 e1 = __builtin_elementwise_max(md45, md67);
    f32x2 e  = __builtin_elementwise_max(e0, e1);
    float bv = fmaxf(e.x, e.y);
    // in-wave max via DPP (VALU, no LDS): full max in lane 63
    float wm = bv;
    DPPMAX(wm, 0x111);  // row_shr:1
    DPPMAX(wm, 0x112);  // row_shr:2
    DPPMAX(wm, 0x114);  // row_shr:4
    DPPMAX(wm, 0x118);  // row_shr:8
    DPPMAX(wm, 0x142);  // row_bcast:15
    DPPMAX(wm, 0x143);  // row_bcast:31
    const float wmax = __int_as_float(
        __builtin_amdgcn_readlane(__float_as_int(wm), 63));
    // lowest tied lane = smallest n (lane ascending == n ascending per wave)
    unsigned long long tied = __ballot(bv == wmax);
    const int winlane = (int)__builtin_ctzll(tied);
    const int sl = m & 1;
    if (lane == winlane){
      // smallest j with md[j]==bv (descending chain, last-true wins)
      int bj = 7;
      if (md67.x == bv) bj = 6;
      if (md45.y == bv) bj = 5;
      if (md45.x == bv) bj = 4;
      if (md23.y == bv) bj = 3;
      if (md23.x == bv) bj = 2;
      if (md01.y == bv) bj = 1;
      if (md01.x == bv) bj = 0;
      // extract coords of point bj from registers (3-level select)
      f32x2 sx = (bj & 4) ? ((bj & 2) ? px67 : px45) : ((bj & 2) ? px23 : px01);
      f32x2 sy = (bj & 4) ? ((bj & 2) ? py67 : py45) : ((bj & 2) ? py23 : py01);
      f32x2 sz = (bj & 4) ? ((bj & 2) ? pz67 : pz45) : ((bj & 2) ? pz23 : pz01);
      float wx = (bj & 1) ? sx.y : sx.x;
      float wy = (bj & 1) ? sy.y : sy.x;
      float wz = (bj & 1) ? sz.y : sz.x;
      int wn = tid * 8 + bj;
      sv_[sl][wv] = ((unsigned long long)__float_as_uint(wmax) << 32)
                  | (unsigned)(4095 - wn);     // (4095-n): smaller n wins on tie
      sc_[sl][wv] = make_float4(wx, wy, wz, 0.0f);
    }
    __syncthreads();
    // 8-slot max tree carrying coords; all pk distinct => total order
    unsigned long long p0 = sv_[sl][0], p1 = sv_[sl][1], p2 = sv_[sl][2], p3 = sv_[sl][3];
    unsigned long long p4 = sv_[sl][4], p5 = sv_[sl][5], p6 = sv_[sl][6], p7 = sv_[sl][7];
    float4 c0 = sc_[sl][0], c1 = sc_[sl][1], c2 = sc_[sl][2], c3 = sc_[sl][3];
    float4 c4 = sc_[sl][4], c5 = sc_[sl][5], c6 = sc_[sl][6], c7 = sc_[sl][7];
    if (p1 > p0){ p0 = p1; c0 = c1; }
    if (p3 > p2){ p2 = p3; c2 = c3; }
    if (p5 > p4){ p4 = p5; c4 = c5; }
    if (p7 > p6){ p6 = p7; c6 = c7; }
    if (p2 > p0){ p0 = p2; c0 = c2; }
    if (p6 > p4){ p4 = p6; c4 = c6; }
    if (p4 > p0){ p0 = p4; c0 = c4; }
    far = 4095 - (int)(p0 & 0xffffffffu);
    cx = c0.x; cy = c0.y; cz = c0.z;
  }
  __syncthreads();
  for (int t = tid; t < M_; t += 512){
    int id = inds_s[t];
    size_t o = ((size_t)b * M_ + t) * 3;
    newxyz[o] = xs[id]; newxyz[o + 1] = ys[id]; newxyz[o + 2] = zs[id];
  }
}

// ---------------- Ball query: one wave per centroid ------------------------
// fmaf chains match XLA's ffp-contract codegen (R2, exact).
__global__ __launch_bounds__(256) void ballq_kernel(const float* __restrict__ xyz,
                                                    const float* __restrict__ newxyz,
                                                    int* __restrict__ gi,
                                                    float* __restrict__ gif){
  const int gw = (blockIdx.x * 256 + threadIdx.x) >> 6;
  const int lane = threadIdx.x & 63;
  const int b = gw >> 10, m = gw & 1023;
  const float* xb = xyz + (size_t)b * N_ * 3;
  const size_t no = (size_t)b * M_ + m;
  const float cx = newxyz[no * 3], cy = newxyz[no * 3 + 1], cz = newxyz[no * 3 + 2];
  const float sm = fmaf(cz, cz, fmaf(cy, cy, cx * cx));
  int total = 0, first_idx = 0; bool havef = false;
  int*   gd = gi  + no * K_;
  float* fd = gif + no * K_;
  for (int ch = 0; ch < 64 && total < K_; ++ch){
    const int n = ch * 64 + lane;
    const float x = xb[n * 3], y = xb[n * 3 + 1], z = xb[n * 3 + 2];
    const float sn = fmaf(z, z, fmaf(y, y, x * x));
    const float dt = fmaf(z, cz, fmaf(y, cy, x * cx));
    float d2 = (sm + sn) - 2.0f * dt;                 // ref: |a|^2+|b|^2-2ab
    float dist = sqrtf(fmaxf(d2, 0.0f));
    bool pred = !(dist > 0.2f);
    unsigned long long mask = __ballot(pred);
    if (!havef && mask){ havef = true; first_idx = ch * 64 + (int)__builtin_ctzll(mask); }
    if (pred){
      int rank = total + (int)__popcll(mask & ((1ull << lane) - 1ull));
      if (rank < K_){ gd[rank] = n; fd[rank] = (float)n; }
    }
    total += (int)__popcll(mask);
  }
  if (total < K_ && lane >= total && lane < K_){ gd[lane] = first_idx; fd[lane] = (float)first_idx; }
}

// ---------------- MLP pass (gather / bn-in, store+stats / stats / maxpool) --
// MIN_: 0 = gather feats from xyz/points, 1 = read h_in (bf16) + BN + ReLU
// MOUT_: 0 = store h (bf16) + partial stats, 1 = partial stats only,
//        2 = BN + ReLU + max-pool over K -> out
template<int CIN, int COUT, int MIN_, int MOUT_>
__global__ __launch_bounds__(256) void mlp_pass(
    const float* __restrict__ xyz, const float* __restrict__ points,
    const float* __restrict__ newxyz, const int* __restrict__ gi,
    const unsigned short* __restrict__ hin, const float* __restrict__ bnin,
    const float* __restrict__ W,
    unsigned short* __restrict__ hout, float* __restrict__ part,
    const float* __restrict__ bncur, float* __restrict__ out)
{
  constexpr int OPT = COUT / 8;
  static_assert(OPT % 4 == 0, "OPT");
  __shared__ __align__(16) float Wt[CIN][COUT];
  __shared__ __align__(16) float ft[CIN][128];
  const int tid = threadIdx.x, blk = blockIdx.x;
  const size_t s0 = (size_t)blk * 128;

  for (int i = tid; i < CIN * COUT; i += 256){
    int o = i / CIN, c = i - o * CIN;
    Wt[c][o] = W[i];
  }

  if constexpr (MIN_ == 0){
    __shared__ int gidx[128];
    __shared__ float nx[4][3];
    const int b  = (int)(s0 >> 15);                 // 32768 samples per batch
    const int m0 = ((int)(s0 & 32767)) >> 5;        // 4 m's per block
    if (tid < 128) gidx[tid] = gi[(size_t)b * 32768 + (size_t)m0 * K_ + tid];
    if (tid < 12){
      int mi = tid / 3, c = tid - mi * 3;
      nx[mi][c] = newxyz[((size_t)b * M_ + m0 + mi) * 3 + c];
    }
    __syncthreads();
    const int sl = tid >> 1, half = tid & 1;
    const int g = gidx[sl];
    const float* ps = points + ((size_t)b * N_ + g) * CPTS_ + half * 32;
    #pragma unroll
    for (int j = 0; j < 8; ++j){
      float4 v = *reinterpret_cast<const float4*>(ps + j * 4);
      int c = 3 + half * 32 + j * 4;
      ft[c][sl] = v.x; ft[c + 1][sl] = v.y; ft[c + 2][sl] = v.z; ft[c + 3][sl] = v.w;
    }
    if (half == 0){
      const float* xp = xyz + ((size_t)b * N_ + g) * 3;
      const int mi = sl >> 5;
      ft[0][sl] = xp[0] - nx[mi][0];
      ft[1][sl] = xp[1] - nx[mi][1];
      ft[2][sl] = xp[2] - nx[mi][2];
    }
  } else {
    const int sl = tid >> 1, c0 = (tid & 1) * 32;
    const unsigned short* hp = hin + (s0 + sl) * CIN + c0;
    #pragma unroll
    for (int j = 0; j < 4; ++j){
      ushort8 raw = *reinterpret_cast<const ushort8*>(hp + j * 8);
      #pragma unroll
      for (int e = 0; e < 8; ++e){
        int c = c0 + j * 8 + e;
        float h = bf2f(raw[e]);
        float f = h * bnin[c] + bnin[CIN + c];
        ft[c][sl] = fmaxf(f, 0.0f);
      }
    }
  }
  __syncthreads();

  const int sg = tid & 31, og = tid >> 5;
  float acc[4][OPT];
  #pragma unroll
  for (int i = 0; i < 4; ++i)
    #pragma unroll
    for (int o = 0; o < OPT; ++o) acc[i][o] = 0.0f;

  #pragma unroll 2
  for (int c = 0; c < CIN; ++c){
    float4 f = *reinterpret_cast<const float4*>(&ft[c][sg * 4]);
    float4 w[OPT / 4];
    #pragma unroll
    for (int j = 0; j < OPT / 4; ++j)
      w[j] = *reinterpret_cast<const float4*>(&Wt[c][og * OPT + j * 4]);
    const float fv[4] = {f.x, f.y, f.z, f.w};
    #pragma unroll
    for (int i = 0; i < 4; ++i){
      #pragma unroll
      for (int j = 0; j < OPT / 4; ++j){
        acc[i][j * 4 + 0] += fv[i] * w[j].x;
        acc[i][j * 4 + 1] += fv[i] * w[j].y;
        acc[i][j * 4 + 2] += fv[i] * w[j].z;
        acc[i][j * 4 + 3] += fv[i] * w[j].w;
      }
    }
  }

  if constexpr (MOUT_ == 0 || MOUT_ == 1){
    if constexpr (MOUT_ == 0){
      #pragma unroll
      for (int i = 0; i < 4; ++i){
        size_t s = s0 + sg * 4 + i;
        unsigned pk[OPT / 2];
        #pragma unroll
        for (int o = 0; o < OPT / 2; ++o)
          pk[o] = f2bf(acc[i][2 * o]) | (f2bf(acc[i][2 * o + 1]) << 16);
        uint4* dst = reinterpret_cast<uint4*>(hout + s * COUT + og * OPT);
        dst[0] = make_uint4(pk[0], pk[1], pk[2], pk[3]);
        if constexpr (OPT == 16) dst[1] = make_uint4(pk[4], pk[5], pk[6], pk[7]);
      }
    }
    float sv[OPT], sq[OPT];
    #pragma unroll
    for (int o = 0; o < OPT; ++o){
      float a0 = acc[0][o], a1 = acc[1][o], a2 = acc[2][o], a3 = acc[3][o];
      sv[o] = ((a0 + a1) + a2) + a3;
      sq[o] = ((a0 * a0 + a1 * a1) + a2 * a2) + a3 * a3;
    }
    #pragma unroll
    for (int off = 1; off < 32; off <<= 1){
      #pragma unroll
      for (int o = 0; o < OPT; ++o){
        sv[o] += __shfl_xor(sv[o], off);
        sq[o] += __shfl_xor(sq[o], off);
      }
    }
    if (sg == 0){
      #pragma unroll
      for (int o = 0; o < OPT; ++o){
        int ch = og * OPT + o;
        part[(size_t)(ch * 2) * 4096 + blk]     = sv[o];
        part[(size_t)(ch * 2 + 1) * 4096 + blk] = sq[o];
      }
    }
  } else {
    const int mloc = sg >> 3;
    float mx[OPT];
    #pragma unroll
    for (int o = 0; o < OPT; ++o){
      int ch = og * OPT + o;
      float a = bncur[ch], sh = bncur[COUT + ch];
      float v0 = fmaxf(acc[0][o] * a + sh, 0.0f);
      float v1 = fmaxf(acc[1][o] * a + sh, 0.0f);
      float v2 = fmaxf(acc[2][o] * a + sh, 0.0f);
      float v3 = fmaxf(acc[3][o] * a + sh, 0.0f);
      mx[o] = fmaxf(fmaxf(v0, v1), fmaxf(v2, v3));
    }
    #pragma unroll
    for (int off = 1; off < 8; off <<= 1)
      #pragma unroll
      for (int o = 0; o < OPT; ++o)
        mx[o] = fmaxf(mx[o], __shfl_xor(mx[o], off));
    if ((sg & 7) == 0){
      size_t mf = (s0 >> 5) + mloc;
      float* dst = out + mf * COUT + og * OPT;
      #pragma unroll
      for (int j = 0; j < OPT / 4; ++j)
        *reinterpret_cast<float4*>(dst + j * 4) =
            make_float4(mx[j * 4], mx[j * 4 + 1], mx[j * 4 + 2], mx[j * 4 + 3]);
    }
  }
}

// ---------------- BN stats reduce + scale/shift -----------------------------
__global__ __launch_bounds__(256) void reduce_stats(const float* __restrict__ part,
                                                    const float* __restrict__ g,
                                                    const float* __restrict__ bb,
                                                    float* __restrict__ bn, int cout){
  const int ch = blockIdx.x, tid = threadIdx.x;
  float s = 0.f, q = 0.f;
  const float* ps = part + (size_t)(ch * 2) * 4096;
  const float* pq = part + (size_t)(ch * 2 + 1) * 4096;
  for (int i = tid; i < 4096; i += 256){ s += ps[i]; q += pq[i]; }
  #pragma unroll
  for (int off = 1; off < 64; off <<= 1){ s += __shfl_xor(s, off); q += __shfl_xor(q, off); }
  __shared__ float as_[4], aq_[4];
  if ((tid & 63) == 0){ as_[tid >> 6] = s; aq_[tid >> 6] = q; }
  __syncthreads();
  if (tid == 0){
    float S = as_[0] + as_[1] + as_[2] + as_[3];
    float Q = aq_[0] + aq_[1] + aq_[2] + aq_[3];
    const float cnt = 524288.0f;
    float mean = S / cnt;
    float var  = Q / cnt - mean * mean;
    float sc = g[ch] / sqrtf(var + 1e-5f);
    bn[ch] = sc;
    bn[cout + ch] = bb[ch] - mean * sc;
  }
}

// ---------------- Max-pool from stored h2 (full-ws path) --------------------
__global__ __launch_bounds__(128) void maxpool_kernel(const unsigned short* __restrict__ h2,
                                                      const float* __restrict__ bn2,
                                                      float* __restrict__ out){
  const int mf = blockIdx.x, ch = threadIdx.x;
  const float a = bn2[ch], sh = bn2[128 + ch];
  const unsigned short* hp = h2 + (size_t)mf * 32 * 128 + ch;
  float mx = 0.0f;                       // ReLU outputs are >= 0
  #pragma unroll 8
  for (int k = 0; k < 32; ++k){
    float v = bf2f(hp[(size_t)k * 128]);
    mx = fmaxf(mx, fmaxf(v * a + sh, 0.0f));
  }
  out[(size_t)mf * 128 + ch] = mx;
}

extern "C" void kernel_launch(void* const* d_in, const int* in_sizes, int n_in,
                              void* d_out, int out_size, void* d_ws, size_t ws_size,
                              hipStream_t stream){
  (void)in_sizes; (void)n_in; (void)out_size;
  const float* xyz    = (const float*)d_in[0];
  const float* points = (const float*)d_in[1];
  const float* W0 = (const float*)d_in[2];
  const float* g0 = (const float*)d_in[3];
  const float* b0 = (const float*)d_in[4];
  const float* W1 = (const float*)d_in[5];
  const float* g1 = (const float*)d_in[6];
  const float* b1 = (const float*)d_in[7];
  const float* W2 = (const float*)d_in[8];
  const float* g2 = (const float*)d_in[9];
  const float* b2 = (const float*)d_in[10];

  float* out = (float*)d_out;
  float* o_newxyz = out;
  float* o_newpts = out + (size_t)B_ * M_ * 3;
  float* o_gind   = out + (size_t)B_ * M_ * 3 + (size_t)B_ * M_ * 128;

  char* ws = (char*)d_ws;
  int*   gi   = (int*)(ws + 0);                         // 2 MB
  float* part = (float*)(ws + (2u << 20));              // 4 MB
  float* bn0  = (float*)(ws + (6u << 20));
  float* bn1  = (float*)(ws + (6u << 20) + 1024);
  float* bn2  = (float*)(ws + (6u << 20) + 2048);
  unsigned short* h0 = (unsigned short*)(ws + (8u << 20));                    // 64 MB
  unsigned short* h1 = (unsigned short*)(ws + (8u << 20) + 67108864ull);      // 64 MB
  unsigned short* h2 = (unsigned short*)(ws + (8u << 20) + 2ull * 67108864ull); // 128 MB
  const bool full = ws_size >= ((8ull << 20) + 2ull * 67108864ull + 134217728ull);

  fps_kernel<<<16, 512, 0, stream>>>(xyz, o_newxyz);
  ballq_kernel<<<4096, 256, 0, stream>>>(xyz, o_newxyz, gi, o_gind);

  mlp_pass<67, 64, 0, 0><<<4096, 256, 0, stream>>>(xyz, points, o_newxyz, gi,
      nullptr, nullptr, W0, h0, part, nullptr, nullptr);
  reduce_stats<<<64, 256, 0, stream>>>(part, g0, b0, bn0, 64);

  mlp_pass<64, 64, 1, 0><<<4096, 256, 0, stream>>>(xyz, points, o_newxyz, gi,
      h0, bn0, W1, h1, part, nullptr, nullptr);
  reduce_stats<<<64, 256, 0, stream>>>(part, g1, b1, bn1, 64);

  if (full){
    mlp_pass<64, 128, 1, 0><<<4096, 256, 0, stream>>>(xyz, points, o_newxyz, gi,
        h1, bn1, W2, h2, part, nullptr, nullptr);
    reduce_stats<<<128, 256, 0, stream>>>(part, g2, b2, bn2, 128);
    maxpool_kernel<<<16384, 128, 0, stream>>>(h2, bn2, o_newpts);
  } else {
    mlp_pass<64, 128, 1, 1><<<4096, 256, 0, stream>>>(xyz, points, o_newxyz, gi,
        h1, bn1, W2, nullptr, part, nullptr, nullptr);
    reduce_stats<<<128, 256, 0, stream>>>(part, g2, b2, bn2, 128);
    mlp_pass<64, 128, 1, 2><<<4096, 256, 0, stream>>>(xyz, points, o_newxyz, gi,
        h1, bn1, W2, nullptr, nullptr, bn2, o_newpts);
  }
}

// Round 9
// 1095.441 us; speedup vs baseline: 1.4457x; 1.4457x over previous
//
#include <hip/hip_runtime.h>
#include <hip/hip_bf16.h>
#include <cstdint>

#define B_ 16
#define N_ 4096
#define CPTS_ 64
#define M_ 1024
#define K_ 32
#define MF_TOT 2097152   // B_*M_*128 pooled outputs

using ushort8 = __attribute__((ext_vector_type(8))) unsigned short;

static __device__ __forceinline__ unsigned f2bf(float x){
  unsigned u = __float_as_uint(x);
  return (u + 0x7fffu + ((u >> 16) & 1u)) >> 16;   // RTNE
}
static __device__ __forceinline__ float bf2f(unsigned short u){
  return __uint_as_float(((unsigned)u) << 16);
}

// DPP max step: v = max(v, dpp_shift(v)). Values are >= 0 so 0-fill is identity.
#define DPPMAX(v, ctrl)                                                        \
  do {                                                                         \
    int _t = __builtin_amdgcn_update_dpp(0, __float_as_int(v), (ctrl), 0xf,    \
                                         0xf, true);                           \
    (v) = fmaxf((v), __int_as_float(_t));                                      \
  } while (0)

// One distance update, all indices compile-time constant (named float4 comps).
#define STEP(MD, PX, PY, PZ, C, J)                                             \
  { float dx = PX.C - cx, dy = PY.C - cy, dz = PZ.C - cz;                      \
    float d = dx * dx; d = d + dy * dy; d = d + dz * dz;                       \
    float nm = fminf(MD.C, d); MD.C = nm;                                      \
    if (nm > bv){ bv = nm; bj = (J); } }
#define STEP4(MD, PX, PY, PZ, J0)                                              \
  STEP(MD, PX, PY, PZ, x, J0)                                                  \
  STEP(MD, PX, PY, PZ, y, (J0) + 1)                                            \
  STEP(MD, PX, PY, PZ, z, (J0) + 2)                                            \
  STEP(MD, PX, PY, PZ, w, (J0) + 3)

// ---------------- FPS: R7 version verbatim (670 us, proven exact) -----------
__global__ __launch_bounds__(512, 1) void fps_kernel(const float* __restrict__ xyz,
                                                     float* __restrict__ newxyz){
#pragma clang fp contract(off)
  __shared__ float xs[N_], ys[N_], zs[N_];
  __shared__ int inds_s[M_];
  __shared__ unsigned long long sv_[2][8];
  const int b = blockIdx.x, tid = threadIdx.x;
  const int lane = tid & 63, wv = tid >> 6;
  const float* xb = xyz + (size_t)b * N_ * 3;
  for (int i = tid; i < N_ * 3; i += 512){
    float v = xb[i];
    int n = i / 3, c = i - n * 3;
    if (c == 0) xs[n] = v; else if (c == 1) ys[n] = v; else zs[n] = v;
  }
  __syncthreads();
  // per-lane points: n = tid*8 + j  (wave w owns [w*512, w*512+512))
  const float4 px0 = *reinterpret_cast<const float4*>(&xs[tid * 8 + 0]);
  const float4 px1 = *reinterpret_cast<const float4*>(&xs[tid * 8 + 4]);
  const float4 py0 = *reinterpret_cast<const float4*>(&ys[tid * 8 + 0]);
  const float4 py1 = *reinterpret_cast<const float4*>(&ys[tid * 8 + 4]);
  const float4 pz0 = *reinterpret_cast<const float4*>(&zs[tid * 8 + 0]);
  const float4 pz1 = *reinterpret_cast<const float4*>(&zs[tid * 8 + 4]);
  float4 md0 = make_float4(1e10f, 1e10f, 1e10f, 1e10f);
  float4 md1 = md0;
  int far = 0;
  float cx = xs[0], cy = ys[0], cz = zs[0];
  for (int m = 0; m < M_; ++m){
    if (tid == 0) inds_s[m] = far;
    float bv = -1.0f; int bj = 0;
    STEP4(md0, px0, py0, pz0, 0)
    STEP4(md1, px1, py1, pz1, 4)
    // in-wave max via DPP (VALU, no LDS): result in lane 63
    float wm = bv;
    DPPMAX(wm, 0x111);  // row_shr:1
    DPPMAX(wm, 0x112);  // row_shr:2
    DPPMAX(wm, 0x114);  // row_shr:4
    DPPMAX(wm, 0x118);  // row_shr:8
    DPPMAX(wm, 0x142);  // row_bcast:15
    DPPMAX(wm, 0x143);  // row_bcast:31
    const float wmax = __int_as_float(
        __builtin_amdgcn_readlane(__float_as_int(wm), 63));
    // lowest tied lane = smallest n (lane ascending == n ascending per wave)
    unsigned long long tied = __ballot(bv == wmax);
    const int winlane = (int)__builtin_ctzll(tied);
    const int sl = m & 1;
    if (lane == winlane){
      int wn = tid * 8 + bj;
      sv_[sl][wv] = ((unsigned long long)__float_as_uint(wmax) << 32)
                  | (unsigned)(4095 - wn);     // (4095-n): smaller n wins on tie
    }
    __syncthreads();
    // 8-slot max tree; all pk distinct (distinct indices) => total order
    unsigned long long p0 = sv_[sl][0], p1 = sv_[sl][1], p2 = sv_[sl][2], p3 = sv_[sl][3];
    unsigned long long p4 = sv_[sl][4], p5 = sv_[sl][5], p6 = sv_[sl][6], p7 = sv_[sl][7];
    if (p1 > p0) p0 = p1;
    if (p3 > p2) p2 = p3;
    if (p5 > p4) p4 = p5;
    if (p7 > p6) p6 = p7;
    if (p2 > p0) p0 = p2;
    if (p6 > p4) p4 = p6;
    if (p4 > p0) p0 = p4;
    far = 4095 - (int)(p0 & 0xffffffffu);
    cx = xs[far]; cy = ys[far]; cz = zs[far];   // broadcast LDS reads
  }
  __syncthreads();
  for (int t = tid; t < M_; t += 512){
    int id = inds_s[t];
    size_t o = ((size_t)b * M_ + t) * 3;
    newxyz[o] = xs[id]; newxyz[o + 1] = ys[id]; newxyz[o + 2] = zs[id];
  }
}

// ---------------- Ball query: one wave per centroid ------------------------
// fmaf chains match XLA's ffp-contract codegen (R2, exact).
__global__ __launch_bounds__(256) void ballq_kernel(const float* __restrict__ xyz,
                                                    const float* __restrict__ newxyz,
                                                    int* __restrict__ gi,
                                                    float* __restrict__ gif){
  const int gw = (blockIdx.x * 256 + threadIdx.x) >> 6;
  const int lane = threadIdx.x & 63;
  const int b = gw >> 10, m = gw & 1023;
  const float* xb = xyz + (size_t)b * N_ * 3;
  const size_t no = (size_t)b * M_ + m;
  const float cx = newxyz[no * 3], cy = newxyz[no * 3 + 1], cz = newxyz[no * 3 + 2];
  const float sm = fmaf(cz, cz, fmaf(cy, cy, cx * cx));
  int total = 0, first_idx = 0; bool havef = false;
  int*   gd = gi  + no * K_;
  float* fd = gif + no * K_;
  for (int ch = 0; ch < 64 && total < K_; ++ch){
    const int n = ch * 64 + lane;
    const float x = xb[n * 3], y = xb[n * 3 + 1], z = xb[n * 3 + 2];
    const float sn = fmaf(z, z, fmaf(y, y, x * x));
    const float dt = fmaf(z, cz, fmaf(y, cy, x * cx));
    float d2 = (sm + sn) - 2.0f * dt;                 // ref: |a|^2+|b|^2-2ab
    float dist = sqrtf(fmaxf(d2, 0.0f));
    bool pred = !(dist > 0.2f);
    unsigned long long mask = __ballot(pred);
    if (!havef && mask){ havef = true; first_idx = ch * 64 + (int)__builtin_ctzll(mask); }
    if (pred){
      int rank = total + (int)__popcll(mask & ((1ull << lane) - 1ull));
      if (rank < K_){ gd[rank] = n; fd[rank] = (float)n; }
    }
    total += (int)__popcll(mask);
  }
  if (total < K_ && lane >= total && lane < K_){ gd[lane] = first_idx; fd[lane] = (float)first_idx; }
}

// ---------------- MLP pass ---------------------------------------------------
// MIN_: 0 = gather feats from xyz/points, 1 = read h_in (bf16) + BN + ReLU
// MOUT_: 0 = store h (bf16) + partial stats
//        1 = partial stats only
//        2 = BN + ReLU + max-pool over K -> out (fallback path)
//        4 = partial stats + raw-h max/min over K (f32) -> out (mx | mn)
template<int CIN, int COUT, int MIN_, int MOUT_>
__global__ __launch_bounds__(256) void mlp_pass(
    const float* __restrict__ xyz, const float* __restrict__ points,
    const float* __restrict__ newxyz, const int* __restrict__ gi,
    const unsigned short* __restrict__ hin, const float* __restrict__ bnin,
    const float* __restrict__ W,
    unsigned short* __restrict__ hout, float* __restrict__ part,
    const float* __restrict__ bncur, float* __restrict__ out)
{
  constexpr int OPT = COUT / 8;
  static_assert(OPT % 4 == 0, "OPT");
  __shared__ __align__(16) float Wt[CIN][COUT];
  __shared__ __align__(16) float ft[CIN][128];
  const int tid = threadIdx.x, blk = blockIdx.x;
  const size_t s0 = (size_t)blk * 128;

  for (int i = tid; i < CIN * COUT; i += 256){
    int o = i / CIN, c = i - o * CIN;
    Wt[c][o] = W[i];
  }

  if constexpr (MIN_ == 0){
    __shared__ int gidx[128];
    __shared__ float nx[4][3];
    const int b  = (int)(s0 >> 15);                 // 32768 samples per batch
    const int m0 = ((int)(s0 & 32767)) >> 5;        // 4 m's per block
    if (tid < 128) gidx[tid] = gi[(size_t)b * 32768 + (size_t)m0 * K_ + tid];
    if (tid < 12){
      int mi = tid / 3, c = tid - mi * 3;
      nx[mi][c] = newxyz[((size_t)b * M_ + m0 + mi) * 3 + c];
    }
    __syncthreads();
    const int sl = tid >> 1, half = tid & 1;
    const int g = gidx[sl];
    const float* ps = points + ((size_t)b * N_ + g) * CPTS_ + half * 32;
    #pragma unroll
    for (int j = 0; j < 8; ++j){
      float4 v = *reinterpret_cast<const float4*>(ps + j * 4);
      int c = 3 + half * 32 + j * 4;
      ft[c][sl] = v.x; ft[c + 1][sl] = v.y; ft[c + 2][sl] = v.z; ft[c + 3][sl] = v.w;
    }
    if (half == 0){
      const float* xp = xyz + ((size_t)b * N_ + g) * 3;
      const int mi = sl >> 5;
      ft[0][sl] = xp[0] - nx[mi][0];
      ft[1][sl] = xp[1] - nx[mi][1];
      ft[2][sl] = xp[2] - nx[mi][2];
    }
  } else {
    const int sl = tid >> 1, c0 = (tid & 1) * 32;
    const unsigned short* hp = hin + (s0 + sl) * CIN + c0;
    #pragma unroll
    for (int j = 0; j < 4; ++j){
      ushort8 raw = *reinterpret_cast<const ushort8*>(hp + j * 8);
      #pragma unroll
      for (int e = 0; e < 8; ++e){
        int c = c0 + j * 8 + e;
        float h = bf2f(raw[e]);
        float f = h * bnin[c] + bnin[CIN + c];
        ft[c][sl] = fmaxf(f, 0.0f);
      }
    }
  }
  __syncthreads();

  const int sg = tid & 31, og = tid >> 5;
  float acc[4][OPT];
  #pragma unroll
  for (int i = 0; i < 4; ++i)
    #pragma unroll
    for (int o = 0; o < OPT; ++o) acc[i][o] = 0.0f;

  #pragma unroll 2
  for (int c = 0; c < CIN; ++c){
    float4 f = *reinterpret_cast<const float4*>(&ft[c][sg * 4]);
    float4 w[OPT / 4];
    #pragma unroll
    for (int j = 0; j < OPT / 4; ++j)
      w[j] = *reinterpret_cast<const float4*>(&Wt[c][og * OPT + j * 4]);
    const float fv[4] = {f.x, f.y, f.z, f.w};
    #pragma unroll
    for (int i = 0; i < 4; ++i){
      #pragma unroll
      for (int j = 0; j < OPT / 4; ++j){
        acc[i][j * 4 + 0] += fv[i] * w[j].x;
        acc[i][j * 4 + 1] += fv[i] * w[j].y;
        acc[i][j * 4 + 2] += fv[i] * w[j].z;
        acc[i][j * 4 + 3] += fv[i] * w[j].w;
      }
    }
  }

  if constexpr (MOUT_ == 0 || MOUT_ == 1 || MOUT_ == 4){
    if constexpr (MOUT_ == 0){
      #pragma unroll
      for (int i = 0; i < 4; ++i){
        size_t s = s0 + sg * 4 + i;
        unsigned pk[OPT / 2];
        #pragma unroll
        for (int o = 0; o < OPT / 2; ++o)
          pk[o] = f2bf(acc[i][2 * o]) | (f2bf(acc[i][2 * o + 1]) << 16);
        uint4* dst = reinterpret_cast<uint4*>(hout + s * COUT + og * OPT);
        dst[0] = make_uint4(pk[0], pk[1], pk[2], pk[3]);
        if constexpr (OPT == 16) dst[1] = make_uint4(pk[4], pk[5], pk[6], pk[7]);
      }
    }
    float sv[OPT], sq[OPT];
    #pragma unroll
    for (int o = 0; o < OPT; ++o){
      float a0 = acc[0][o], a1 = acc[1][o], a2 = acc[2][o], a3 = acc[3][o];
      sv[o] = ((a0 + a1) + a2) + a3;
      sq[o] = ((a0 * a0 + a1 * a1) + a2 * a2) + a3 * a3;
    }
    #pragma unroll
    for (int off = 1; off < 32; off <<= 1){
      #pragma unroll
      for (int o = 0; o < OPT; ++o){
        sv[o] += __shfl_xor(sv[o], off);
        sq[o] += __shfl_xor(sq[o], off);
      }
    }
    if (sg == 0){
      #pragma unroll
      for (int o = 0; o < OPT; ++o){
        int ch = og * OPT + o;
        part[(size_t)(ch * 2) * 4096 + blk]     = sv[o];
        part[(size_t)(ch * 2 + 1) * 4096 + blk] = sq[o];
      }
    }
    if constexpr (MOUT_ == 4){
      // raw-h max & min over K=32 (f32): 4 local samples, then 8-thread group
      float amx[OPT], amn[OPT];
      #pragma unroll
      for (int o = 0; o < OPT; ++o){
        amx[o] = fmaxf(fmaxf(acc[0][o], acc[1][o]), fmaxf(acc[2][o], acc[3][o]));
        amn[o] = fminf(fminf(acc[0][o], acc[1][o]), fminf(acc[2][o], acc[3][o]));
      }
      #pragma unroll
      for (int off = 1; off < 8; off <<= 1){
        #pragma unroll
        for (int o = 0; o < OPT; ++o){
          amx[o] = fmaxf(amx[o], __shfl_xor(amx[o], off));
          amn[o] = fminf(amn[o], __shfl_xor(amn[o], off));
        }
      }
      if ((sg & 7) == 0){
        size_t mf = (s0 >> 5) + (sg >> 3);
        float* dmx = out + mf * COUT + og * OPT;
        float* dmn = dmx + MF_TOT;
        #pragma unroll
        for (int j = 0; j < OPT / 4; ++j){
          *reinterpret_cast<float4*>(dmx + j * 4) =
              make_float4(amx[j * 4], amx[j * 4 + 1], amx[j * 4 + 2], amx[j * 4 + 3]);
          *reinterpret_cast<float4*>(dmn + j * 4) =
              make_float4(amn[j * 4], amn[j * 4 + 1], amn[j * 4 + 2], amn[j * 4 + 3]);
        }
      }
    }
  } else {
    const int mloc = sg >> 3;
    float mx[OPT];
    #pragma unroll
    for (int o = 0; o < OPT; ++o){
      int ch = og * OPT + o;
      float a = bncur[ch], sh = bncur[COUT + ch];
      float v0 = fmaxf(acc[0][o] * a + sh, 0.0f);
      float v1 = fmaxf(acc[1][o] * a + sh, 0.0f);
      float v2 = fmaxf(acc[2][o] * a + sh, 0.0f);
      float v3 = fmaxf(acc[3][o] * a + sh, 0.0f);
      mx[o] = fmaxf(fmaxf(v0, v1), fmaxf(v2, v3));
    }
    #pragma unroll
    for (int off = 1; off < 8; off <<= 1)
      #pragma unroll
      for (int o = 0; o < OPT; ++o)
        mx[o] = fmaxf(mx[o], __shfl_xor(mx[o], off));
    if ((sg & 7) == 0){
      size_t mf = (s0 >> 5) + mloc;
      float* dst = out + mf * COUT + og * OPT;
      #pragma unroll
      for (int j = 0; j < OPT / 4; ++j)
        *reinterpret_cast<float4*>(dst + j * 4) =
            make_float4(mx[j * 4], mx[j * 4 + 1], mx[j * 4 + 2], mx[j * 4 + 3]);
    }
  }
}

// ---------------- BN stats reduce + scale/shift -----------------------------
__global__ __launch_bounds__(256) void reduce_stats(const float* __restrict__ part,
                                                    const float* __restrict__ g,
                                                    const float* __restrict__ bb,
                                                    float* __restrict__ bn, int cout){
  const int ch = blockIdx.x, tid = threadIdx.x;
  float s = 0.f, q = 0.f;
  const float* ps = part + (size_t)(ch * 2) * 4096;
  const float* pq = part + (size_t)(ch * 2 + 1) * 4096;
  for (int i = tid; i < 4096; i += 256){ s += ps[i]; q += pq[i]; }
  #pragma unroll
  for (int off = 1; off < 64; off <<= 1){ s += __shfl_xor(s, off); q += __shfl_xor(q, off); }
  __shared__ float as_[4], aq_[4];
  if ((tid & 63) == 0){ as_[tid >> 6] = s; aq_[tid >> 6] = q; }
  __syncthreads();
  if (tid == 0){
    float S = as_[0] + as_[1] + as_[2] + as_[3];
    float Q = aq_[0] + aq_[1] + aq_[2] + aq_[3];
    const float cnt = 524288.0f;
    float mean = S / cnt;
    float var  = Q / cnt - mean * mean;
    float sc = g[ch] / sqrtf(var + 1e-5f);
    bn[ch] = sc;
    bn[cout + ch] = bb[ch] - mean * sc;
  }
}

// ---------------- finish: out = relu(max(a*mx+sh, a*mn+sh)) -----------------
__global__ __launch_bounds__(256) void bn_minmax_finish(const float* __restrict__ mxmn,
                                                        const float* __restrict__ bn2,
                                                        float* __restrict__ out){
  const int i = blockIdx.x * 256 + threadIdx.x;
  const int ch = i & 127;
  const float a = bn2[ch], sh = bn2[128 + ch];
  const float mx = mxmn[i], mn = mxmn[MF_TOT + i];
  out[i] = fmaxf(fmaxf(mx * a + sh, mn * a + sh), 0.0f);
}

// ---------------- Max-pool from stored h2 (fallback path only) --------------
__global__ __launch_bounds__(128) void maxpool_kernel(const unsigned short* __restrict__ h2,
                                                      const float* __restrict__ bn2,
                                                      float* __restrict__ out){
  const int mf = blockIdx.x, ch = threadIdx.x;
  const float a = bn2[ch], sh = bn2[128 + ch];
  const unsigned short* hp = h2 + (size_t)mf * 32 * 128 + ch;
  float mx = 0.0f;                       // ReLU outputs are >= 0
  #pragma unroll 8
  for (int k = 0; k < 32; ++k){
    float v = bf2f(hp[(size_t)k * 128]);
    mx = fmaxf(mx, fmaxf(v * a + sh, 0.0f));
  }
  out[(size_t)mf * 128 + ch] = mx;
}

extern "C" void kernel_launch(void* const* d_in, const int* in_sizes, int n_in,
                              void* d_out, int out_size, void* d_ws, size_t ws_size,
                              hipStream_t stream){
  (void)in_sizes; (void)n_in; (void)out_size;
  const float* xyz    = (const float*)d_in[0];
  const float* points = (const float*)d_in[1];
  const float* W0 = (const float*)d_in[2];
  const float* g0 = (const float*)d_in[3];
  const float* b0 = (const float*)d_in[4];
  const float* W1 = (const float*)d_in[5];
  const float* g1 = (const float*)d_in[6];
  const float* b1 = (const float*)d_in[7];
  const float* W2 = (const float*)d_in[8];
  const float* g2 = (const float*)d_in[9];
  const float* b2 = (const float*)d_in[10];

  float* out = (float*)d_out;
  float* o_newxyz = out;
  float* o_newpts = out + (size_t)B_ * M_ * 3;
  float* o_gind   = out + (size_t)B_ * M_ * 3 + (size_t)B_ * M_ * 128;

  char* ws = (char*)d_ws;
  int*   gi   = (int*)(ws + 0);                         // 2 MB
  float* part = (float*)(ws + (2u << 20));              // 4 MB
  float* bn0  = (float*)(ws + (6u << 20));
  float* bn1  = (float*)(ws + (6u << 20) + 1024);
  float* bn2  = (float*)(ws + (6u << 20) + 2048);
  unsigned short* h0 = (unsigned short*)(ws + (8u << 20));                    // 64 MB
  unsigned short* h1 = (unsigned short*)(ws + (8u << 20) + 67108864ull);      // 64 MB
  float* mxmn = (float*)(ws + (8u << 20) + 2ull * 67108864ull);               // 16 MB
  unsigned short* h2 = (unsigned short*)(ws + (8u << 20) + 2ull * 67108864ull); // fallback reuse
  const size_t need_new = (8ull << 20) + 2ull * 67108864ull + 2ull * MF_TOT * 4ull;
  const bool newpath = ws_size >= need_new;

  fps_kernel<<<16, 512, 0, stream>>>(xyz, o_newxyz);
  ballq_kernel<<<4096, 256, 0, stream>>>(xyz, o_newxyz, gi, o_gind);

  mlp_pass<67, 64, 0, 0><<<4096, 256, 0, stream>>>(xyz, points, o_newxyz, gi,
      nullptr, nullptr, W0, h0, part, nullptr, nullptr);
  reduce_stats<<<64, 256, 0, stream>>>(part, g0, b0, bn0, 64);

  mlp_pass<64, 64, 1, 0><<<4096, 256, 0, stream>>>(xyz, points, o_newxyz, gi,
      h0, bn0, W1, h1, part, nullptr, nullptr);
  reduce_stats<<<64, 256, 0, stream>>>(part, g1, b1, bn1, 64);

  if (newpath){
    mlp_pass<64, 128, 1, 4><<<4096, 256, 0, stream>>>(xyz, points, o_newxyz, gi,
        h1, bn1, W2, nullptr, part, nullptr, mxmn);
    reduce_stats<<<128, 256, 0, stream>>>(part, g2, b2, bn2, 128);
    bn_minmax_finish<<<MF_TOT / 256, 256, 0, stream>>>(mxmn, bn2, o_newpts);
  } else {
    mlp_pass<64, 128, 1, 1><<<4096, 256, 0, stream>>>(xyz, points, o_newxyz, gi,
        h1, bn1, W2, nullptr, part, nullptr, nullptr);
    reduce_stats<<<128, 256, 0, stream>>>(part, g2, b2, bn2, 128);
    mlp_pass<64, 128, 1, 2><<<4096, 256, 0, stream>>>(xyz, points, o_newxyz, gi,
        h1, bn1, W2, nullptr, nullptr, bn2, o_newpts);
  }
}